// Round 11
// baseline (617.901 us; speedup 1.0000x reference)
//
#include <hip/hip_runtime.h>
#include <math.h>

#define NMODELS 64
#define HID     64
#define TILE    64          // samples per block (4 waves x 16)
#define MAX_TILES 576       // 32768/64 + 64 = 8 * 72
#define XCHUNK  72

// workspace layout (int32 indices)
#define WS_NT    0
#define WS_HIST  16
#define WS_CUR   96
#define WS_TILES 192        // 3 ints per tile
#define WS_SEL   4096
#define WS_PERM  36864

// output layout (float32 indices)
#define OUT_SEL  393216
#define OUT_LOG  425984
#define OUT_PROB 2523136

__global__ void k_init(int* __restrict__ wsi) {
  if (threadIdx.x < NMODELS) wsi[WS_HIST + threadIdx.x] = 0;
}

// routing + constant fills (logits=1, probs=1/64) in one pass
__global__ void k_route(const float* __restrict__ in, float* __restrict__ out,
                        int* __restrict__ wsi) {
  __shared__ int lh[NMODELS];
  int t = threadIdx.x;
  if (t < NMODELS) lh[t] = 0;
  __syncthreads();
  int b = blockIdx.x * 256 + t;          // 0..32767

  {
    float4 one = make_float4(1.f, 1.f, 1.f, 1.f);
    float4 pr  = make_float4(0.015625f, 0.015625f, 0.015625f, 0.015625f);
    float4* lg = reinterpret_cast<float4*>(out + OUT_LOG);
    float4* pb = reinterpret_cast<float4*>(out + OUT_PROB);
    #pragma unroll
    for (int k = 0; k < 16; ++k) {
      lg[k * 32768 + b] = one;
      pb[k * 32768 + b] = pr;
    }
  }

  float x = in[b * 6 + 0];
  float z = in[b * 6 + 2];
  const float TWO_PI = 6.283185307179586476925286766559f;
  // f64 atan2 rounded to f32 ~= correctly-rounded f32 atan2 (matches numpy);
  // remaining chain is IEEE-exact f32, bit-identical to the reference.
  float ang = (float)atan2((double)z, (double)x);
  float tt  = ang + TWO_PI;
  float m   = fmodf(tt, TWO_PI);
  float a   = m / TWO_PI * 64.0f;
  int e = (int)floorf(a);
  e = e < 0 ? 0 : (e > 63 ? 63 : e);
  out[OUT_SEL + b] = (float)e;
  wsi[WS_SEL + b]  = e;
  atomicAdd(&lh[e], 1);
  __syncthreads();
  if (t < NMODELS && lh[t] > 0) atomicAdd(&wsi[WS_HIST + t], lh[t]);
}

__global__ void k_prefix(int* __restrict__ wsi) {  // 1 block, 64 threads
  int t = threadIdx.x;      // t = expert id
  int c = wsi[WS_HIST + t];
  int x = c;
  #pragma unroll
  for (int d = 1; d < 64; d <<= 1) {
    int y = __shfl_up(x, d, 64);
    if (t >= d) x += y;
  }
  int off = x - c;
  wsi[WS_CUR + t] = off;
  int ntile_me = (c + TILE - 1) >> 6;
  int tx = ntile_me;
  #pragma unroll
  for (int d = 1; d < 64; d <<= 1) {
    int y = __shfl_up(tx, d, 64);
    if (t >= d) tx += y;
  }
  int tbase = tx - ntile_me;
  for (int k = 0; k < ntile_me; ++k) {
    int rem = c - k * TILE;
    wsi[WS_TILES + (tbase + k) * 3 + 0] = t;
    wsi[WS_TILES + (tbase + k) * 3 + 1] = off + k * TILE;
    wsi[WS_TILES + (tbase + k) * 3 + 2] = rem < TILE ? rem : TILE;
  }
  if (t == 63) wsi[WS_NT] = tx;
}

__global__ void k_scatter(int* __restrict__ wsi) {
  __shared__ int lc[NMODELS];
  __shared__ int lbase[NMODELS];
  int t = threadIdx.x;
  if (t < NMODELS) lc[t] = 0;
  __syncthreads();
  int b = blockIdx.x * 256 + t;
  int e = wsi[WS_SEL + b];
  int r = atomicAdd(&lc[e], 1);
  __syncthreads();
  if (t < NMODELS) {
    int c = lc[t];
    lbase[t] = (c > 0) ? atomicAdd(&wsi[WS_CUR + t], c) : 0;
  }
  __syncthreads();
  wsi[WS_PERM + lbase[e] + r] = b;
}

// Column-per-lane MLP: lane j holds W[:,j] in 64 VGPRs; activations are read
// from LDS at wave-uniform addresses (free broadcast). Each wave owns 16
// samples end-to-end -> zero barriers, wave-private double buffer.
__global__ __launch_bounds__(256, 4) void k_main(
    const float* __restrict__ in,
    const float* __restrict__ W0, const float* __restrict__ b0,
    const float* __restrict__ W1, const float* __restrict__ b1,
    const float* __restrict__ W2, const float* __restrict__ b2,
    const float* __restrict__ W3, const float* __restrict__ b3,
    const float* __restrict__ W4, const float* __restrict__ b4,
    const int* __restrict__ wsi, float* __restrict__ out) {
  __shared__ __align__(16) float LB[4][2][16 * 64];   // 32 KB/block

  int g = (blockIdx.x & 7) * XCHUNK + (blockIdx.x >> 3);   // XCD swizzle (576=8*72)
  if (g >= wsi[WS_NT]) return;
  int e     = __builtin_amdgcn_readfirstlane(wsi[WS_TILES + g * 3 + 0]);
  int start = __builtin_amdgcn_readfirstlane(wsi[WS_TILES + g * 3 + 1]);
  int cnt   = __builtin_amdgcn_readfirstlane(wsi[WS_TILES + g * 3 + 2]);

  int wv = threadIdx.x >> 6;
  int lane = threadIdx.x & 63;
  if (cnt <= wv * 16) return;               // wave-uniform, no barriers in kernel
  float* A = LB[wv][0];
  float* B = LB[wv][1];

  int idx = -1;
  if (lane < 16 && (wv * 16 + lane) < cnt) idx = wsi[WS_PERM + start + wv * 16 + lane];

  // head weight columns (lane = j) and biases
  float v4s0 = W4[lane * 3 + 0], v4s1 = W4[lane * 3 + 1], v4s2 = W4[lane * 3 + 2];
  const float* W4e = W4 + (size_t)(e + 1) * 192;
  float v4e0 = W4e[lane * 3 + 0], v4e1 = W4e[lane * 3 + 1], v4e2 = W4e[lane * 3 + 2];
  const float* b4e = b4 + (e + 1) * 3;
  float bs0 = b4[0], bs1 = b4[1], bs2 = b4[2];
  float be0 = b4e[0], be1 = b4e[1], be2 = b4e[2];

  // stage x (16 samples x 6) into A cols 0..5
  #pragma unroll
  for (int k = 0; k < 2; ++k) {
    int kk = lane + k * 64;
    if (kk < 96) {
      int s = kk / 6, c = kk - s * 6;
      int id = __shfl(idx, s);
      A[s * 64 + c] = (id >= 0) ? in[(size_t)id * 6 + c] : 0.0f;
    }
  }

  float w[64];
  auto LOADW = [&](const float* Wp) {
    #pragma unroll
    for (int i = 0; i < 64; ++i) w[i] = Wp[(i << 6) + lane];
  };
  auto CORE = [&](const float* SRC, float bias, int s0,
                  float& a0, float& a1, float& a2, float& a3) {
    a0 = bias; a1 = bias; a2 = bias; a3 = bias;
    #pragma unroll
    for (int i0 = 0; i0 < 64; i0 += 4) {
      float4 c0 = *(const float4*)(SRC + (s0 + 0) * 64 + i0);
      float4 c1 = *(const float4*)(SRC + (s0 + 1) * 64 + i0);
      float4 c2 = *(const float4*)(SRC + (s0 + 2) * 64 + i0);
      float4 c3 = *(const float4*)(SRC + (s0 + 3) * 64 + i0);
      a0 = fmaf(c0.x, w[i0], a0); a0 = fmaf(c0.y, w[i0 + 1], a0);
      a0 = fmaf(c0.z, w[i0 + 2], a0); a0 = fmaf(c0.w, w[i0 + 3], a0);
      a1 = fmaf(c1.x, w[i0], a1); a1 = fmaf(c1.y, w[i0 + 1], a1);
      a1 = fmaf(c1.z, w[i0 + 2], a1); a1 = fmaf(c1.w, w[i0 + 3], a1);
      a2 = fmaf(c2.x, w[i0], a2); a2 = fmaf(c2.y, w[i0 + 1], a2);
      a2 = fmaf(c2.z, w[i0 + 2], a2); a2 = fmaf(c2.w, w[i0 + 3], a2);
      a3 = fmaf(c3.x, w[i0], a3); a3 = fmaf(c3.y, w[i0 + 1], a3);
      a3 = fmaf(c3.z, w[i0 + 2], a3); a3 = fmaf(c3.w, w[i0 + 3], a3);
    }
  };
  auto MM = [&](const float* SRC, float* DST, float bias) {
    #pragma unroll
    for (int s0 = 0; s0 < 16; s0 += 4) {
      float a0, a1, a2, a3;
      CORE(SRC, bias, s0, a0, a1, a2, a3);
      DST[(s0 + 0) * 64 + lane] = fmaxf(a0, 0.0f);
      DST[(s0 + 1) * 64 + lane] = fmaxf(a1, 0.0f);
      DST[(s0 + 2) * 64 + lane] = fmaxf(a2, 0.0f);
      DST[(s0 + 3) * 64 + lane] = fmaxf(a3, 0.0f);
    }
  };
  auto RED = [&](float& v) {
    v += __shfl_xor(v, 1);  v += __shfl_xor(v, 2);  v += __shfl_xor(v, 4);
    v += __shfl_xor(v, 8);  v += __shfl_xor(v, 16); v += __shfl_xor(v, 32);
  };

  // ---- L0: x(6) -> h1, in-place into A ----
  {
    #pragma unroll
    for (int i = 0; i < 6; ++i) w[i] = W0[(i << 6) + lane];
    float bb = b0[lane];
    #pragma unroll
    for (int s0 = 0; s0 < 16; s0 += 4) {
      float4 c0 = *(const float4*)(A + (s0 + 0) * 64);
      float4 c1 = *(const float4*)(A + (s0 + 1) * 64);
      float4 c2 = *(const float4*)(A + (s0 + 2) * 64);
      float4 c3 = *(const float4*)(A + (s0 + 3) * 64);
      float2 d0 = *(const float2*)(A + (s0 + 0) * 64 + 4);
      float2 d1 = *(const float2*)(A + (s0 + 1) * 64 + 4);
      float2 d2 = *(const float2*)(A + (s0 + 2) * 64 + 4);
      float2 d3 = *(const float2*)(A + (s0 + 3) * 64 + 4);
      float a0 = bb, a1 = bb, a2 = bb, a3 = bb;
      a0 = fmaf(c0.x, w[0], a0); a0 = fmaf(c0.y, w[1], a0); a0 = fmaf(c0.z, w[2], a0);
      a0 = fmaf(c0.w, w[3], a0); a0 = fmaf(d0.x, w[4], a0); a0 = fmaf(d0.y, w[5], a0);
      a1 = fmaf(c1.x, w[0], a1); a1 = fmaf(c1.y, w[1], a1); a1 = fmaf(c1.z, w[2], a1);
      a1 = fmaf(c1.w, w[3], a1); a1 = fmaf(d1.x, w[4], a1); a1 = fmaf(d1.y, w[5], a1);
      a2 = fmaf(c2.x, w[0], a2); a2 = fmaf(c2.y, w[1], a2); a2 = fmaf(c2.z, w[2], a2);
      a2 = fmaf(c2.w, w[3], a2); a2 = fmaf(d2.x, w[4], a2); a2 = fmaf(d2.y, w[5], a2);
      a3 = fmaf(c3.x, w[0], a3); a3 = fmaf(c3.y, w[1], a3); a3 = fmaf(c3.z, w[2], a3);
      a3 = fmaf(c3.w, w[3], a3); a3 = fmaf(d3.x, w[4], a3); a3 = fmaf(d3.y, w[5], a3);
      A[(s0 + 0) * 64 + lane] = fmaxf(a0, 0.0f);
      A[(s0 + 1) * 64 + lane] = fmaxf(a1, 0.0f);
      A[(s0 + 2) * 64 + lane] = fmaxf(a2, 0.0f);
      A[(s0 + 3) * 64 + lane] = fmaxf(a3, 0.0f);
    }
  }

  // ---- L1: h1(A) -> h2(B) ----
  LOADW(W1);
  MM(A, B, b1[lane]);

  // ---- L2 shared: h2(B) -> h3s(A) ----
  LOADW(W2);
  MM(B, A, b2[lane]);

  // ---- L2 expert: h2(B) -> h3e(B) in-place ----
  LOADW(W2 + (size_t)(e + 1) * 4096);
  MM(B, B, b2[(e + 1) * 64 + lane]);

  // ---- L3 shared from h3s(A): h4ss -> lod0 (w4s) + lod1 (w4e) ----
  LOADW(W3);
  {
    float bb = b3[lane];
    #pragma unroll
    for (int s0 = 0; s0 < 16; s0 += 4) {
      float a0, a1, a2, a3;
      CORE(A, bb, s0, a0, a1, a2, a3);
      float hh0 = fmaxf(a0, 0.0f), hh1 = fmaxf(a1, 0.0f);
      float hh2 = fmaxf(a2, 0.0f), hh3 = fmaxf(a3, 0.0f);
      #pragma unroll
      for (int t = 0; t < 4; ++t) {
        float h = (t == 0) ? hh0 : (t == 1) ? hh1 : (t == 2) ? hh2 : hh3;
        float p0 = h * v4s0, p1 = h * v4s1, p2 = h * v4s2;
        float p3 = h * v4e0, p4 = h * v4e1, p5 = h * v4e2;
        RED(p0); RED(p1); RED(p2); RED(p3); RED(p4); RED(p5);
        int id = __shfl(idx, s0 + t);
        if (lane == 0 && id >= 0) {
          float* op = out + (size_t)id * 12;
          *(float4*)op = make_float4(p0 + bs0, p1 + bs1, p2 + bs2, p3 + be0);
          *(float2*)(op + 4) = make_float2(p4 + be1, p5 + be2);
        }
      }
    }
  }

  // ---- L3 expert ----
  LOADW(W3 + (size_t)(e + 1) * 4096);
  {
    float bb = b3[(e + 1) * 64 + lane];
    // from h3s(A): h4se -> lod2 (w4e)
    #pragma unroll
    for (int s0 = 0; s0 < 16; s0 += 4) {
      float a0, a1, a2, a3;
      CORE(A, bb, s0, a0, a1, a2, a3);
      float hh0 = fmaxf(a0, 0.0f), hh1 = fmaxf(a1, 0.0f);
      float hh2 = fmaxf(a2, 0.0f), hh3 = fmaxf(a3, 0.0f);
      #pragma unroll
      for (int t = 0; t < 4; ++t) {
        float h = (t == 0) ? hh0 : (t == 1) ? hh1 : (t == 2) ? hh2 : hh3;
        float p0 = h * v4e0, p1 = h * v4e1, p2 = h * v4e2;
        RED(p0); RED(p1); RED(p2);
        int id = __shfl(idx, s0 + t);
        if (lane == 0 && id >= 0) {
          float* op = out + (size_t)id * 12;
          *(float2*)(op + 6) = make_float2(p0 + be0, p1 + be1);
          op[8] = p2 + be2;
        }
      }
    }
    // from h3e(B): h4ee -> lod3 (w4e)
    #pragma unroll
    for (int s0 = 0; s0 < 16; s0 += 4) {
      float a0, a1, a2, a3;
      CORE(B, bb, s0, a0, a1, a2, a3);
      float hh0 = fmaxf(a0, 0.0f), hh1 = fmaxf(a1, 0.0f);
      float hh2 = fmaxf(a2, 0.0f), hh3 = fmaxf(a3, 0.0f);
      #pragma unroll
      for (int t = 0; t < 4; ++t) {
        float h = (t == 0) ? hh0 : (t == 1) ? hh1 : (t == 2) ? hh2 : hh3;
        float p0 = h * v4e0, p1 = h * v4e1, p2 = h * v4e2;
        RED(p0); RED(p1); RED(p2);
        int id = __shfl(idx, s0 + t);
        if (lane == 0 && id >= 0) {
          float* op = out + (size_t)id * 12;
          op[9] = p0 + be0;
          *(float2*)(op + 10) = make_float2(p1 + be1, p2 + be2);
        }
      }
    }
  }
}

extern "C" void kernel_launch(void* const* d_in, const int* in_sizes, int n_in,
                              void* d_out, int out_size, void* d_ws, size_t ws_size,
                              hipStream_t stream) {
  const float* in = (const float*)d_in[0];
  const float* W0 = (const float*)d_in[1];
  const float* b0 = (const float*)d_in[2];
  const float* W1 = (const float*)d_in[3];
  const float* b1 = (const float*)d_in[4];
  const float* W2 = (const float*)d_in[5];
  const float* b2 = (const float*)d_in[6];
  const float* W3 = (const float*)d_in[7];
  const float* b3 = (const float*)d_in[8];
  const float* W4 = (const float*)d_in[9];
  const float* b4 = (const float*)d_in[10];
  float* out = (float*)d_out;
  int* wsi = (int*)d_ws;

  hipLaunchKernelGGL(k_init,    dim3(1),    dim3(64),  0, stream, wsi);
  hipLaunchKernelGGL(k_route,   dim3(128),  dim3(256), 0, stream, in, out, wsi);
  hipLaunchKernelGGL(k_prefix,  dim3(1),    dim3(64),  0, stream, wsi);
  hipLaunchKernelGGL(k_scatter, dim3(128),  dim3(256), 0, stream, wsi);
  hipLaunchKernelGGL(k_main,    dim3(MAX_TILES), dim3(256), 0, stream,
                     in, W0, b0, W1, b1, W2, b2, W3, b3, W4, b4, wsi, out);
}